// Round 5
// baseline (463.984 us; speedup 1.0000x reference)
//
#include <hip/hip_runtime.h>
#include <math.h>

#define DD 128
#define CAPB 2048            // per-bucket capacity; mean ~1024 at E/N=16, 64-node buckets
#define MAXNB 1600           // max buckets (N <= 102400)

typedef __attribute__((ext_vector_type(8))) short bf16x8;
typedef __attribute__((ext_vector_type(4))) float f32x4;

__device__ __forceinline__ unsigned short f2bf(float f) {
    unsigned u = __float_as_uint(f);
    unsigned r = u + 0x7FFF + ((u >> 16) & 1);
    return (unsigned short)(r >> 16);
}
__device__ __forceinline__ float bf2f(unsigned short h) {
    return __uint_as_float(((unsigned)h) << 16);
}

// fast sigmoid/tanh: v_exp_f32 + v_rcp_f32 (~1e-6 rel err, saturates correctly)
__device__ __forceinline__ float fsigm(float x) {
    float e = __builtin_amdgcn_exp2f(-1.442695041f * x);
    return __builtin_amdgcn_rcpf(1.0f + e);
}
__device__ __forceinline__ float ftanh(float x) {
    float e = __builtin_amdgcn_exp2f(2.885390082f * x);   // exp(2x)
    return 1.0f - 2.0f * __builtin_amdgcn_rcpf(1.0f + e);
}

// async global->LDS, 16B per lane; LDS dest = wave-uniform base + lane*16
__device__ __forceinline__ void gld16(const unsigned short* g, unsigned short* l) {
    __builtin_amdgcn_global_load_lds(
        (const __attribute__((address_space(1))) void*)g,
        (__attribute__((address_space(3))) void*)l, 16, 0, 0);
}

__global__ void k_wsfail(float* __restrict__ out, float val, int n) {
    int i = blockIdx.x * 256 + threadIdx.x;
    if (i < n) out[i] = (i == 0) ? val : 0.0f;
}

// ---------------------------------------------------------------------------
// k_setup: detect + zero sums/gCur + w1T/w2T transposes + x->AGG[,256:384)
// ---------------------------------------------------------------------------
__global__ void k_setup(const int* __restrict__ e32, int* __restrict__ flag,
                        float* __restrict__ sums, int* __restrict__ gCur, int NB,
                        const float* __restrict__ W1, const float* __restrict__ W2,
                        unsigned short* __restrict__ w1T, unsigned short* __restrict__ w2T,
                        const float* __restrict__ x, unsigned short* __restrict__ AGG,
                        int total_x4) {
    const int bid = blockIdx.x;
    const int t = threadIdx.x;
    if (bid == 0) {
        if (t == 0) {
            int f = 1;
            for (int i = 1; i < 16; i += 2) f &= (e32[i] == 0);
            *flag = f;  // 1 => int64 edges
        }
        for (int i = t; i < 768; i += 256) sums[i] = 0.0f;
    } else if (bid < 8) {
        int i = (bid - 1) * 256 + t;
        if (i < NB) gCur[i] = 0;
    } else if (bid < 136) {
        int i = (bid - 8) * 256 + t;   // < 32768
        int j = i >> 7, k = i & 127;
        w1T[j * 128 + k] = f2bf(W1[k * 256 + j]);
    } else if (bid < 264) {
        int i = (bid - 136) * 256 + t; // < 32768
        int j = i >> 8, k = i & 255;
        w2T[j * 256 + k] = f2bf(W2[k * 128 + j]);
    } else {
        int idx = (bid - 264) * 256 + t;
        if (idx < total_x4) {
            int i = idx >> 5, j4 = (idx & 31) * 4;
            float4 v = *(const float4*)(x + (size_t)i * 128 + j4);
            unsigned lo = (unsigned)f2bf(v.x) | ((unsigned)f2bf(v.y) << 16);
            unsigned hi = (unsigned)f2bf(v.z) | ((unsigned)f2bf(v.w) << 16);
            unsigned short* p = AGG + (size_t)i * 384 + 256 + j4;
            *(unsigned*)(p) = lo;
            *(unsigned*)(p + 2) = hi;
        }
    }
}

// ---------------------------------------------------------------------------
// k_fusew: fold merge-linear into gate weights (fp32 math, one bf16 rounding)
// Gate-permuted physical columns: pj(d,g) = (d>>4)*64 + g*16 + (d&15)
// ---------------------------------------------------------------------------
__global__ void k_fusew(const float* __restrict__ Wm, const float* __restrict__ Wih,
                        const float* __restrict__ Whh, const float* __restrict__ bm,
                        const float* __restrict__ b_ih, const float* __restrict__ b_hh,
                        unsigned short* __restrict__ BtG, float* __restrict__ biasG) {
    const int j = blockIdx.x;
    const int c = threadIdx.x;
    const int g = j >> 7, d = j & 127;
    const int pj = ((d >> 4) << 6) + (g << 4) + (d & 15);
    float acc = 0.0f;
    if (j < 384) {
        const float* wr = Wih + (size_t)j * 128;
        const float* wc = Wm + (size_t)c * 128;
        for (int m = 0; m < 128; m++) acc += wc[m] * wr[m];
    }
    BtG[(size_t)pj * 384 + c] = f2bf(acc);
    if (c < 128) {
        float v = 0.0f;
        if (j < 256) v = Whh[(size_t)j * 128 + c];
        else if (j >= 384) v = Whh[(size_t)(j - 128) * 128 + c];
        BtG[(size_t)pj * 384 + 256 + c] = f2bf(v);
    }
    if (c == 0) {
        float b;
        if (j < 256) b = b_ih[j] + b_hh[j];
        else if (j < 384) b = b_ih[j];
        else b = b_hh[j - 128];
        if (j < 384) {
            const float* wr = Wih + (size_t)j * 128;
            float dd = 0.0f;
            for (int m = 0; m < 128; m++) dd += bm[m] * wr[m];
            b += dd;
        }
        biasG[pj] = b;
    }
}

// ---------------------------------------------------------------------------
// pass A: bin edges into per-bucket windows (bucket = dst>>6, 64 nodes)
// ---------------------------------------------------------------------------
__global__ __launch_bounds__(256) void k_bin(const void* __restrict__ edges_raw,
                                             const int* __restrict__ flag,
                                             int* __restrict__ gCur,
                                             unsigned* __restrict__ binned,
                                             int E, int Nn, int NB) {
    __shared__ int cnt_[MAXNB];
    __shared__ int cur_[MAXNB];
    const int t = threadIdx.x;
    const int e0 = blockIdx.x * 4096;
    for (int i = t; i < NB; i += 256) cnt_[i] = 0;
    __syncthreads();
    const int is64 = *flag;
    for (int k = 0; k < 16; k++) {
        int e = e0 + k * 256 + t;
        if (e < E) {
            int d = is64 ? (int)((const long long*)edges_raw)[(size_t)E + e]
                         : ((const int*)edges_raw)[(size_t)E + e];
            d = min(max(d, 0), Nn - 1);
            atomicAdd(&cnt_[d >> 6], 1);
        }
    }
    __syncthreads();
    for (int i = t; i < NB; i += 256) {
        int c = cnt_[i];
        cur_[i] = (c > 0) ? atomicAdd(&gCur[i], c) : 0;
    }
    __syncthreads();
    for (int k = 0; k < 16; k++) {
        int e = e0 + k * 256 + t;
        if (e < E) {
            int s, d;
            if (is64) {
                s = (int)((const long long*)edges_raw)[e];
                d = (int)((const long long*)edges_raw)[(size_t)E + e];
            } else {
                s = ((const int*)edges_raw)[e];
                d = ((const int*)edges_raw)[(size_t)E + e];
            }
            s = min(max(s, 0), Nn - 1);
            d = min(max(d, 0), Nn - 1);
            int b = d >> 6;
            int p = atomicAdd(&cur_[b], 1);
            if (p < CAPB)
                binned[(size_t)b * CAPB + p] = (unsigned)s | ((unsigned)(d & 63) << 23);
        }
    }
}

// ---------------------------------------------------------------------------
// pass B: per 64-node bucket, LDS CSR, gather-aggregate into AGG cols 0..255
// 2-edges-per-load gather: lanes 0-31 = edge e (8B/lane, 4 cols), lanes
// 32-63 = edge e+1; 8-deep unroll -> 16 edges / 4KB in flight per wave.
// Final __shfl_xor(32) combine; half0 stores sum row, half1 stores max row.
// ---------------------------------------------------------------------------
__global__ __launch_bounds__(256) void k_bagg(const unsigned* __restrict__ binned,
                                              const int* __restrict__ gCur,
                                              const void* __restrict__ edges_raw,
                                              const int* __restrict__ flag,
                                              unsigned short* __restrict__ AGG,
                                              int E, int Nn) {
    __shared__ unsigned lsrc[CAPB];
    __shared__ int deg_[64], off_[64], cur2_[64];
    __shared__ int sa[64], sb[64];
    const int t = threadIdx.x;
    const int wave = t >> 6;
    const int lane = t & 63;
    const int b = blockIdx.x;
    const int node0 = b << 6;
    const int nloc = min(64, Nn - node0);
    const int cnt = gCur[b];
    const int half = lane >> 5;
    const int hl = lane & 31;
    const unsigned c8 = (unsigned)hl * 8u;    // byte offset within 256-B x row
    const int c2 = lane * 2;                  // for slow path

    if (cnt <= CAPB) {
        if (t < 64) deg_[t] = 0;
        __syncthreads();
        for (int i = t; i < cnt; i += 256)
            atomicAdd(&deg_[binned[(size_t)b * CAPB + i] >> 23], 1);
        __syncthreads();
        if (t < 64) sa[t] = deg_[t];
        __syncthreads();
        for (int off = 1; off < 64; off <<= 1) {
            if (t < 64) sb[t] = sa[t] + ((t >= off) ? sa[t - off] : 0);
            __syncthreads();
            if (t < 64) sa[t] = sb[t];
            __syncthreads();
        }
        if (t < 64) {
            off_[t] = sa[t] - deg_[t];
            cur2_[t] = off_[t];
        }
        __syncthreads();
        for (int i = t; i < cnt; i += 256) {
            unsigned e = binned[(size_t)b * CAPB + i];
            int dl = e >> 23;
            int p = atomicAdd(&cur2_[dl], 1);
            lsrc[p] = (e & 0x7FFFFF) * 768u + 512u;   // byte offset of x-row
        }
        __syncthreads();
        const char* AGGb = (const char*)AGG;
        for (int ln = wave; ln < nloc; ln += 4) {
            const int o = off_[ln];
            const int d = deg_[ln];
            float s0 = 0.f, s1 = 0.f, s2 = 0.f, s3 = 0.f;
            float m0 = -INFINITY, m1 = -INFINITY, m2 = -INFINITY, m3 = -INFINITY;
            int e = 0;
            for (; e + 15 < d; e += 16) {
                uint2 v[8];
#pragma unroll
                for (int u = 0; u < 8; u++)
                    v[u] = *(const uint2*)(AGGb + lsrc[o + e + 2 * u + half] + c8);
#pragma unroll
                for (int u = 0; u < 8; u++) {
                    float a = bf2f((unsigned short)(v[u].x & 0xffff));
                    float bb = bf2f((unsigned short)(v[u].x >> 16));
                    float cc = bf2f((unsigned short)(v[u].y & 0xffff));
                    float dd2 = bf2f((unsigned short)(v[u].y >> 16));
                    s0 += a; s1 += bb; s2 += cc; s3 += dd2;
                    m0 = fmaxf(m0, a); m1 = fmaxf(m1, bb);
                    m2 = fmaxf(m2, cc); m3 = fmaxf(m3, dd2);
                }
            }
            for (; e + 1 < d; e += 2) {
                uint2 v = *(const uint2*)(AGGb + lsrc[o + e + half] + c8);
                float a = bf2f((unsigned short)(v.x & 0xffff));
                float bb = bf2f((unsigned short)(v.x >> 16));
                float cc = bf2f((unsigned short)(v.y & 0xffff));
                float dd2 = bf2f((unsigned short)(v.y >> 16));
                s0 += a; s1 += bb; s2 += cc; s3 += dd2;
                m0 = fmaxf(m0, a); m1 = fmaxf(m1, bb);
                m2 = fmaxf(m2, cc); m3 = fmaxf(m3, dd2);
            }
            if (e < d) {
                // single leftover edge: both halves load it, half 1 neutralized
                uint2 v = *(const uint2*)(AGGb + lsrc[o + e] + c8);
                float a = bf2f((unsigned short)(v.x & 0xffff));
                float bb = bf2f((unsigned short)(v.x >> 16));
                float cc = bf2f((unsigned short)(v.y & 0xffff));
                float dd2 = bf2f((unsigned short)(v.y >> 16));
                float ninf = -INFINITY;
                if (half == 0) {
                    s0 += a; s1 += bb; s2 += cc; s3 += dd2;
                    m0 = fmaxf(m0, a); m1 = fmaxf(m1, bb);
                    m2 = fmaxf(m2, cc); m3 = fmaxf(m3, dd2);
                } else {
                    m0 = fmaxf(m0, ninf);  // no-op, keeps structure
                }
            }
            // combine halves
            s0 += __shfl_xor(s0, 32); s1 += __shfl_xor(s1, 32);
            s2 += __shfl_xor(s2, 32); s3 += __shfl_xor(s3, 32);
            m0 = fmaxf(m0, __shfl_xor(m0, 32)); m1 = fmaxf(m1, __shfl_xor(m1, 32));
            m2 = fmaxf(m2, __shfl_xor(m2, 32)); m3 = fmaxf(m3, __shfl_xor(m3, 32));
            if (d == 0) { m0 = 0.f; m1 = 0.f; m2 = 0.f; m3 = 0.f; }
            unsigned short* row = AGG + (size_t)(node0 + ln) * 384;
            if (half == 0) {
                uint2 sv;
                sv.x = (unsigned)f2bf(s0) | ((unsigned)f2bf(s1) << 16);
                sv.y = (unsigned)f2bf(s2) | ((unsigned)f2bf(s3) << 16);
                *(uint2*)(row + 4 * hl) = sv;
            } else {
                uint2 mv;
                mv.x = (unsigned)f2bf(m0) | ((unsigned)f2bf(m1) << 16);
                mv.y = (unsigned)f2bf(m2) | ((unsigned)f2bf(m3) << 16);
                *(uint2*)(row + 128 + 4 * hl) = mv;
            }
        }
    } else {
        // overflow slow path (formal correctness; ~never taken)
        const int is64 = *flag;
        for (int ln = wave; ln < nloc; ln += 4) {
            const int node = node0 + ln;
            float sx = 0.f, sy = 0.f;
            float mx = -INFINITY, my = -INFINITY;
            int d = 0;
            for (int e = 0; e < E; e++) {
                int dd = is64 ? (int)((const long long*)edges_raw)[(size_t)E + e]
                              : ((const int*)edges_raw)[(size_t)E + e];
                dd = min(max(dd, 0), Nn - 1);
                if (dd == node) {
                    int s = is64 ? (int)((const long long*)edges_raw)[e]
                                 : ((const int*)edges_raw)[e];
                    s = min(max(s, 0), Nn - 1);
                    unsigned v0 = *(const unsigned*)(AGG + (size_t)s * 384 + 256 + c2);
                    float ax = bf2f((unsigned short)(v0 & 0xffff));
                    float ay = bf2f((unsigned short)(v0 >> 16));
                    sx += ax; sy += ay;
                    mx = fmaxf(mx, ax); my = fmaxf(my, ay);
                    d++;
                }
            }
            if (d == 0) { mx = 0.f; my = 0.f; }
            unsigned short* row = AGG + (size_t)node * 384;
            *(unsigned*)(row + c2) = (unsigned)f2bf(sx) | ((unsigned)f2bf(sy) << 16);
            *(unsigned*)(row + 128 + c2) = (unsigned)f2bf(mx) | ((unsigned)f2bf(my) << 16);
        }
    }
}

// ---------------------------------------------------------------------------
// k_gruemm: fused gate GEMM + GRU, BM=256 x BN=128 tile, 4 waves.
// Each wave: 64 rows x 128 cols = acc[4][8], 32 MFMA per K-iter (2x the
// old 128-tile kernel -> half the barrier/latency cost per FLOP).
// Counted-vmcnt 2-deep pipeline (6 gld16 per tile per wave, vmcnt(6)).
// Gate-permuted B cols: within a 128-col block, nt = dh*4+gate, dims
// dimb+dh*16+l16. GRU epilogue in registers -> h bf16 (N x 128).
// ---------------------------------------------------------------------------
__global__ __launch_bounds__(256) void k_gruemm(
    const unsigned short* __restrict__ A,    // AGG, lda=384
    const unsigned short* __restrict__ Bt,   // BtG 512x384 (gate-permuted)
    const float* __restrict__ bias,
    const unsigned short* __restrict__ Xb,   // AGG (x at col 256)
    unsigned short* __restrict__ Cb,         // h, ldc=128
    int M) {
    const int K = 384;
    __shared__ unsigned short LD[2][12288];  // per buf: A[0..8192) B[8192..12288)
    unsigned short* RP = &LD[0][0];          // epilogue repack (256*40=10240)

    const int t = threadIdx.x;
    const int lane = t & 63;
    const int wave = t >> 6;
    const int quad = lane >> 4;
    const int l16 = lane & 15;
    const int sig = (l16 >> 1) & 3;
    const int wr = wave * 64;

    // XCD-grouped bijective remap (m204); ncb = 4 col-blocks
    const int nwg = 4 * gridDim.y;
    int lin = blockIdx.y * 4 + blockIdx.x;
    const int qq = nwg >> 3, rr = nwg & 7;
    const int xcd = lin & 7, pos = lin >> 3;
    const int nl = (xcd < rr ? xcd * (qq + 1) : rr * (qq + 1) + (xcd - rr) * qq) + pos;
    const int j0 = (nl & 3) * 128;
    const int r0 = (nl >> 2) * 256;

    f32x4 acc[4][8];
#pragma unroll
    for (int i = 0; i < 4; i++)
#pragma unroll
        for (int j = 0; j < 8; j++) acc[i][j] = (f32x4){0.f, 0.f, 0.f, 0.f};

    const int rowl = lane >> 2;
    const int gsw8 = (((lane & 3) ^ ((lane >> 3) & 3))) * 8;

    auto stage = [&](int buf, int k0) {
#pragma unroll
        for (int p = 0; p < 4; p++) {        // A: 256 rows, 16 rows per call
            int row = (wave * 4 + p) * 16 + rowl;
            int gr = r0 + row;
            if (gr >= M) gr = M - 1;
            gld16(A + (size_t)gr * 384 + k0 + gsw8,
                  &LD[buf][(wave * 4 + p) * 512]);
        }
#pragma unroll
        for (int p = 0; p < 2; p++) {        // B: 128 rows
            int row = (wave * 2 + p) * 16 + rowl;
            gld16(Bt + (size_t)(j0 + row) * K + k0 + gsw8,
                  &LD[buf][8192 + (wave * 2 + p) * 512]);
        }
    };

    stage(0, 0);
    stage(1, 32);
    for (int k0 = 0; k0 < K; k0 += 32) {
        const int cur = (k0 >> 5) & 1;
        if (k0 + 32 < K)
            asm volatile("s_waitcnt vmcnt(6)\n\ts_barrier" ::: "memory");
        else
            asm volatile("s_waitcnt vmcnt(0)\n\ts_barrier" ::: "memory");
        bf16x8 af[4], bfr[8];
#pragma unroll
        for (int i = 0; i < 4; i++)
            af[i] = *(bf16x8*)&LD[cur][(wr + i * 16 + l16) * 32 + (quad ^ sig) * 8];
#pragma unroll
        for (int i = 0; i < 8; i++)
            bfr[i] = *(bf16x8*)&LD[cur][8192 + (i * 16 + l16) * 32 + (quad ^ sig) * 8];
        asm volatile("s_waitcnt lgkmcnt(0)\n\ts_barrier" ::: "memory");
        if (k0 + 64 < K) stage(cur, k0 + 64);
#pragma unroll
        for (int mt = 0; mt < 4; mt++)
#pragma unroll
            for (int nt = 0; nt < 8; nt++)
                acc[mt][nt] = __builtin_amdgcn_mfma_f32_16x16x32_bf16(
                    af[mt], bfr[nt], acc[mt][nt], 0, 0, 0);
    }

    // ---- GRU epilogue: nt = dh*4 + gate (0:r 1:z 2:i_n 3:h_n) ----
    const int dimb = j0 >> 2;               // 32-dim base for this block
    float bR[2], bZ[2], bI[2], bH[2];
#pragma unroll
    for (int dh = 0; dh < 2; dh++) {
        bR[dh] = bias[j0 + dh * 64 + l16];
        bZ[dh] = bias[j0 + dh * 64 + 16 + l16];
        bI[dh] = bias[j0 + dh * 64 + 32 + l16];
        bH[dh] = bias[j0 + dh * 64 + 48 + l16];
    }
#pragma unroll
    for (int mt = 0; mt < 4; mt++) {
#pragma unroll
        for (int reg = 0; reg < 4; reg++) {
            int rloc = wr + mt * 16 + quad * 4 + reg;
            int grow = r0 + rloc;
            int gi = grow < M ? grow : M - 1;
#pragma unroll
            for (int dh = 0; dh < 2; dh++) {
                float r = fsigm(acc[mt][dh * 4 + 0][reg] + bR[dh]);
                float z = fsigm(acc[mt][dh * 4 + 1][reg] + bZ[dh]);
                float nn = ftanh(acc[mt][dh * 4 + 2][reg] + bI[dh] +
                                 r * (acc[mt][dh * 4 + 3][reg] + bH[dh]));
                float xv = bf2f(Xb[(size_t)gi * 384 + 256 + dimb + dh * 16 + l16]);
                float h = (1.0f - z) * nn + z * xv;
                RP[rloc * 40 + dh * 16 + l16] = f2bf(h);
            }
        }
    }
    __syncthreads();
    // coalesced stores: 256 rows x 32 dims
#pragma unroll
    for (int p = 0; p < 4; p++) {
        int id = p * 256 + t;                // 0..1023 = 256 rows x 4 chunks
        int rloc = id >> 2, ck = id & 3;
        int grow = r0 + rloc;
        if (grow < M)
            *(float4*)(Cb + (size_t)grow * 128 + dimb + ck * 8) =
                *(const float4*)&RP[rloc * 40 + ck * 8];
    }
}

// ---------------------------------------------------------------------------
// bf16 MFMA GEMM, 128x128 tile, 4 waves (G4/G5 backbone layers).
// Non-AFFINE: counted-vmcnt 2-deep pipeline. AFFINE: reg-staged A (BN1).
// ---------------------------------------------------------------------------
template <int AFFINE, int LEAKY, int STATS>
__global__ __launch_bounds__(256) void k_mgemm(
    const unsigned short* __restrict__ A, int lda,
    const unsigned short* __restrict__ Bt,
    const float* __restrict__ bias,
    const float* __restrict__ sumA, const float* __restrict__ sqA,
    const float* __restrict__ gA, const float* __restrict__ beA,
    unsigned short* __restrict__ Cb, int ldc,
    int M, int K, float* __restrict__ sumO, float* __restrict__ sqO, float invN) {
    __shared__ unsigned short ABs[2][2][4096];  // [buf][A|B][128*32]
    __shared__ float sc1[256], sh1[256];
    __shared__ float ssum[128], ssq[128];
    unsigned short* RP = &ABs[0][0][0];         // epilogue repack region

    const int t = threadIdx.x;
    const int lane = t & 63;
    const int wave = t >> 6;
    const int wr = (wave >> 1) * 64;
    const int wc = (wave & 1) * 64;
    const int quad = lane >> 4;
    const int l16 = lane & 15;
    const int sig = (l16 >> 1) & 3;             // fragment-read swizzle

    // XCD-grouped bijective remap (m204)
    const int ncb = gridDim.x;
    const int nwg = ncb * gridDim.y;
    int lin = blockIdx.y * ncb + blockIdx.x;
    const int qq = nwg >> 3, rr = nwg & 7;
    const int xcd = lin & 7, pos = lin >> 3;
    const int nl = (xcd < rr ? xcd * (qq + 1) : rr * (qq + 1) + (xcd - rr) * qq) + pos;
    const int j0 = (nl % ncb) * 128;
    const int r0 = (nl / ncb) * 128;

    if (AFFINE) {
        float m = sumA[t] * invN;
        float v = sqA[t] * invN - m * m;
        if (v < 0.f) v = 0.f;
        float rs = rsqrtf(v + 1e-5f);
        float sc = gA[t] * rs;
        sc1[t] = sc;
        sh1[t] = beA[t] - m * sc;
    }
    if (STATS && t < 128) { ssum[t] = 0.f; ssq[t] = 0.f; }
    if (AFFINE || STATS) __syncthreads();

    f32x4 acc[4][4];
#pragma unroll
    for (int i = 0; i < 4; i++)
#pragma unroll
        for (int j = 0; j < 4; j++) acc[i][j] = (f32x4){0.f, 0.f, 0.f, 0.f};

    const int rowl = lane >> 2;
    const int gsw8 = (((lane & 3) ^ ((lane >> 3) & 3))) * 8;

    const int srow = t >> 2;
    const int sg8 = (t & 3) * 8;
    const int swz8 = (((t & 3) ^ ((t >> 3) & 3))) * 8;
    float4 areg[2];

    auto stageA = [&](int buf, int k0) {
#pragma unroll
        for (int p = 0; p < 2; p++) {
            int row = (wave * 2 + p) * 16 + rowl;
            int gr = r0 + row;
            if (gr >= M) gr = M - 1;
            gld16(A + (size_t)gr * lda + k0 + gsw8,
                  &ABs[buf][0][(wave * 2 + p) * 512]);
        }
    };
    auto stageB = [&](int buf, int k0) {
#pragma unroll
        for (int p = 0; p < 2; p++) {
            int row = (wave * 2 + p) * 16 + rowl;
            gld16(Bt + (size_t)(j0 + row) * K + k0 + gsw8,
                  &ABs[buf][1][(wave * 2 + p) * 512]);
        }
    };
    auto loadA = [&](int k0) {
#pragma unroll
        for (int p = 0; p < 2; p++) {
            int gr = r0 + p * 64 + srow;
            areg[p] = make_float4(0.f, 0.f, 0.f, 0.f);
            if (gr < M) areg[p] = *(const float4*)(A + (size_t)gr * lda + k0 + sg8);
        }
    };
    auto writeA = [&](int buf, int k0) {
        union U8 { float4 f; unsigned short u[8]; } uv;
#pragma unroll
        for (int p = 0; p < 2; p++) {
            uv.f = areg[p];
#pragma unroll
            for (int q = 0; q < 8; q++) {
                float f = bf2f(uv.u[q]) * sc1[k0 + sg8 + q] + sh1[k0 + sg8 + q];
                uv.u[q] = f2bf(f);
            }
            *(float4*)&ABs[buf][0][(p * 64 + srow) * 32 + swz8] = uv.f;
        }
    };

    if (!AFFINE) {
        stageA(0, 0); stageB(0, 0);
        if (32 < K) { stageA(1, 32); stageB(1, 32); }
        for (int k0 = 0; k0 < K; k0 += 32) {
            const int cur = (k0 >> 5) & 1;
            if (k0 + 32 < K)
                asm volatile("s_waitcnt vmcnt(4)\n\ts_barrier" ::: "memory");
            else
                asm volatile("s_waitcnt vmcnt(0)\n\ts_barrier" ::: "memory");
            bf16x8 af[4], bfr[4];
#pragma unroll
            for (int i = 0; i < 4; i++) {
                af[i]  = *(bf16x8*)&ABs[cur][0][(wr + i * 16 + l16) * 32 + (quad ^ sig) * 8];
                bfr[i] = *(bf16x8*)&ABs[cur][1][(wc + i * 16 + l16) * 32 + (quad ^ sig) * 8];
            }
            asm volatile("s_waitcnt lgkmcnt(0)\n\ts_barrier" ::: "memory");
            if (k0 + 64 < K) { stageA(cur, k0 + 64); stageB(cur, k0 + 64); }
#pragma unroll
            for (int mt = 0; mt < 4; mt++)
#pragma unroll
                for (int nt = 0; nt < 4; nt++)
                    acc[mt][nt] = __builtin_amdgcn_mfma_f32_16x16x32_bf16(
                        af[mt], bfr[nt], acc[mt][nt], 0, 0, 0);
        }
    } else {
        loadA(0); writeA(0, 0);
        stageB(0, 0);
        __syncthreads();
        int buf = 0;
        for (int k0 = 0; k0 < K; k0 += 32) {
            const int kn = k0 + 32;
            const bool hasNext = kn < K;
            if (hasNext) {
                loadA(kn);
                stageB(buf ^ 1, kn);
            }
            bf16x8 af[4], bfr[4];
#pragma unroll
            for (int i = 0; i < 4; i++) {
                af[i]  = *(bf16x8*)&ABs[buf][0][(wr + i * 16 + l16) * 32 + (quad ^ sig) * 8];
                bfr[i] = *(bf16x8*)&ABs[buf][1][(wc + i * 16 + l16) * 32 + (quad ^ sig) * 8];
            }
#pragma unroll
            for (int mt = 0; mt < 4; mt++)
#pragma unroll
                for (int nt = 0; nt < 4; nt++)
                    acc[mt][nt] = __builtin_amdgcn_mfma_f32_16x16x32_bf16(
                        af[mt], bfr[nt], acc[mt][nt], 0, 0, 0);
            if (hasNext) writeA(buf ^ 1, kn);
            __syncthreads();
            buf ^= 1;
        }
    }

    // ---- standard epilogue: repack via LDS, coalesced 16B stores ----
#pragma unroll
    for (int half = 0; half < 2; half++) {
        if (wr == half * 64) {
#pragma unroll
            for (int nt = 0; nt < 4; nt++) {
                int colLoc = wc + nt * 16 + l16;
                float bv = bias[j0 + colLoc];
                float s = 0.f, q = 0.f;
#pragma unroll
                for (int mt = 0; mt < 4; mt++) {
#pragma unroll
                    for (int reg = 0; reg < 4; reg++) {
                        int rloc = mt * 16 + quad * 4 + reg;
                        float v = acc[mt][nt][reg] + bv;
                        if (LEAKY) v = (v >= 0.f) ? v : 0.01f * v;
                        if (STATS && (r0 + half * 64 + rloc) < M) { s += v; q += v * v; }
                        RP[rloc * 128 + colLoc] = f2bf(v);
                    }
                }
                if (STATS) {
                    atomicAdd(&ssum[colLoc], s);
                    atomicAdd(&ssq[colLoc], q);
                }
            }
        }
        __syncthreads();
#pragma unroll
        for (int p = 0; p < 4; p++) {
            int id = p * 256 + t;      // 0..1023 = 64 rows x 16 chunks
            int rloc = id >> 4;
            int ck = id & 15;
            int grow = r0 + half * 64 + rloc;
            if (grow < M)
                *(float4*)(Cb + (size_t)grow * ldc + j0 + ck * 8) =
                    *(const float4*)&RP[rloc * 128 + ck * 8];
        }
        __syncthreads();
    }
    if (STATS && t < 128) {
        atomicAdd(&sumO[j0 + t], ssum[t]);
        atomicAdd(&sqO[j0 + t], ssq[t]);
    }
}

// out(fp32) = bf2f(ypre)*scale2 + shift2 (BN2 finalize inline), 4 elems/thread
__global__ void k_affine2(const unsigned short* __restrict__ ypre, float* __restrict__ out,
                          const float* __restrict__ sum2, const float* __restrict__ sq2,
                          const float* __restrict__ g2, const float* __restrict__ be2,
                          int total4, float invN) {
    __shared__ float sc[128], sh[128];
    int t = threadIdx.x;
    if (t < 128) {
        float m = sum2[t] * invN;
        float v = sq2[t] * invN - m * m;
        if (v < 0.f) v = 0.f;
        float rs = rsqrtf(v + 1e-5f);
        float s = g2[t] * rs;
        sc[t] = s;
        sh[t] = be2[t] - m * s;
    }
    __syncthreads();
    int idx = blockIdx.x * 256 + t;
    if (idx >= total4) return;
    int i4 = idx * 4;
    int c = i4 & 127;
    unsigned u0 = *(const unsigned*)(ypre + i4);
    unsigned u1 = *(const unsigned*)(ypre + i4 + 2);
    float4 o;
    o.x = bf2f((unsigned short)(u0 & 0xffff)) * sc[c]     + sh[c];
    o.y = bf2f((unsigned short)(u0 >> 16))    * sc[c + 1] + sh[c + 1];
    o.z = bf2f((unsigned short)(u1 & 0xffff)) * sc[c + 2] + sh[c + 2];
    o.w = bf2f((unsigned short)(u1 >> 16))    * sc[c + 3] + sh[c + 3];
    *(float4*)(out + i4) = o;
}

// ---------------------------------------------------------------------------
extern "C" void kernel_launch(void* const* d_in, const int* in_sizes, int n_in,
                              void* d_out, int out_size, void* d_ws, size_t ws_size,
                              hipStream_t stream) {
    const float* x       = (const float*)d_in[0];
    const void*  edges   = d_in[1];
    const float* W_merge = (const float*)d_in[2];
    const float* b_merge = (const float*)d_in[3];
    const float* W_ih    = (const float*)d_in[4];
    const float* W_hh    = (const float*)d_in[5];
    const float* b_ih    = (const float*)d_in[6];
    const float* b_hh    = (const float*)d_in[7];
    const float* W1      = (const float*)d_in[8];
    const float* b1      = (const float*)d_in[9];
    const float* g1      = (const float*)d_in[10];
    const float* be1     = (const float*)d_in[11];
    const float* W2      = (const float*)d_in[12];
    const float* b2      = (const float*)d_in[13];
    const float* g2      = (const float*)d_in[14];
    const float* be2     = (const float*)d_in[15];

    const int N = in_sizes[0] / DD;
    const int E = in_sizes[1] / 2;
    float* out = (float*)d_out;

    size_t need = ((size_t)640 * N + 120000) * sizeof(float);
    if (ws_size < need) {
        k_wsfail<<<(out_size + 255) / 256, 256, 0, stream>>>(
            out, (float)(ws_size >> 20), out_size);
        return;
    }

    const int NB = (N + 63) >> 6;   // 64-node buckets

    float* ws = (float*)d_ws;
    // [0,192N): AGG bf16 Nx384 (sum|max|x) -> later y1b bf16 Nx256 at [0,128N),
    //                                         ypre bf16 Nx128 at [128N,192N)
    // [448N,512N): h bf16 Nx128
    // [512N,...): binned (NB*CAPB uints) + gCur + weights + sums
    unsigned short* AGG  = (unsigned short*)ws;
    unsigned short* y1b  = (unsigned short*)ws;
    unsigned short* ypre = (unsigned short*)(ws + (size_t)128 * N);
    unsigned short* hb16 = (unsigned short*)(ws + (size_t)448 * N);

    unsigned* binned = (unsigned*)(ws + (size_t)512 * N);
    int* gCur = (int*)(binned + (size_t)NB * CAPB);

    float* wbase = (float*)(gCur + NB + 64);
    unsigned short* BtG = (unsigned short*)wbase;                 // 512*384 el
    unsigned short* w1T = (unsigned short*)(wbase + 98304);       // 32768 el
    unsigned short* w2T = (unsigned short*)(wbase + 98304 + 16384);
    float* biasG = wbase + 98304 + 32768;   // 512
    float* sums  = biasG + 512;             // 768
    float* sum1 = sums, *sq1 = sums + 256, *sum2 = sums + 512, *sq2 = sums + 640;
    int*   flag  = (int*)(sums + 768);

    const int nrb  = (N + 127) / 128;
    const int nrb2 = (N + 255) / 256;
    const int ncvt4 = (N * 32 + 255) / 256;
    const float invN = 1.0f / (float)N;

    // 1. setup (detect, zeros, w1T/w2T, x->AGG)
    k_setup<<<264 + ncvt4, 256, 0, stream>>>(
        (const int*)edges, flag, sums, gCur, NB, W1, W2, w1T, w2T, x, AGG, N * 32);
    // 2. fused gate weights, gate-permuted columns (fp32 dot, one bf16 rounding)
    k_fusew<<<512, 256, 0, stream>>>(W_merge, W_ih, W_hh, b_merge, b_ih, b_hh, BtG, biasG);
    // 3. bin edges
    k_bin<<<(E + 4095) / 4096, 256, 0, stream>>>(edges, flag, gCur, binned, E, N, NB);
    // 4. per-bucket aggregate -> AGG cols 0..255
    k_bagg<<<NB, 256, 0, stream>>>(binned, gCur, edges, flag, AGG, E, N);
    // 5. fused G2'+GRU: h = GRU(AGG @ BtG + biasG, x)  (256-row tiles)
    k_gruemm<<<dim3(4, nrb2), 256, 0, stream>>>(AGG, BtG, biasG, AGG, hb16, N);
    // 6. G4: y1b = leaky(h @ w1T + b1) + stats1  (K=128, F=256)
    k_mgemm<0, 1, 1><<<dim3(2, nrb), 256, 0, stream>>>(
        hb16, 128, w1T, b1, nullptr, nullptr, nullptr, nullptr,
        y1b, 256, N, 128, sum1, sq1, invN);
    // 7. G5: ypre = leaky(bn1(y1b) @ w2T + b2) + stats2  (K=256, F=128)
    k_mgemm<1, 1, 1><<<dim3(1, nrb), 256, 0, stream>>>(
        y1b, 256, w2T, b2, sum1, sq1, g1, be1,
        ypre, 128, N, 256, sum2, sq2, invN);
    // 8. BN2 finalize + affine -> fp32 out (4 elems/thread)
    k_affine2<<<ncvt4, 256, 0, stream>>>(ypre, out, sum2, sq2, g2, be2, N * 32, invN);
}

// Round 7
// 446.753 us; speedup vs baseline: 1.0386x; 1.0386x over previous
//
#include <hip/hip_runtime.h>
#include <math.h>

#define DD 128
#define CAPB 2048            // per-bucket capacity; mean ~1024 at E/N=16, 64-node buckets
#define MAXNB 1600           // max buckets (N <= 102400)

typedef __attribute__((ext_vector_type(8))) short bf16x8;
typedef __attribute__((ext_vector_type(4))) float f32x4;

__device__ __forceinline__ unsigned short f2bf(float f) {
    unsigned u = __float_as_uint(f);
    unsigned r = u + 0x7FFF + ((u >> 16) & 1);
    return (unsigned short)(r >> 16);
}
__device__ __forceinline__ float bf2f(unsigned short h) {
    return __uint_as_float(((unsigned)h) << 16);
}

// fast sigmoid/tanh: v_exp_f32 + v_rcp_f32 (~1e-6 rel err, saturates correctly)
__device__ __forceinline__ float fsigm(float x) {
    float e = __builtin_amdgcn_exp2f(-1.442695041f * x);
    return __builtin_amdgcn_rcpf(1.0f + e);
}
__device__ __forceinline__ float ftanh(float x) {
    float e = __builtin_amdgcn_exp2f(2.885390082f * x);   // exp(2x)
    return 1.0f - 2.0f * __builtin_amdgcn_rcpf(1.0f + e);
}

// async global->LDS, 16B per lane; LDS dest = wave-uniform base + lane*16
__device__ __forceinline__ void gld16(const unsigned short* g, unsigned short* l) {
    __builtin_amdgcn_global_load_lds(
        (const __attribute__((address_space(1))) void*)g,
        (__attribute__((address_space(3))) void*)l, 16, 0, 0);
}

__global__ void k_wsfail(float* __restrict__ out, float val, int n) {
    int i = blockIdx.x * 256 + threadIdx.x;
    if (i < n) out[i] = (i == 0) ? val : 0.0f;
}

// ---------------------------------------------------------------------------
// k_setup: detect + zero sums/gCur + w1T/w2T transposes + x->AGG[,256:384)
// ---------------------------------------------------------------------------
__global__ void k_setup(const int* __restrict__ e32, int* __restrict__ flag,
                        float* __restrict__ sums, int* __restrict__ gCur, int NB,
                        const float* __restrict__ W1, const float* __restrict__ W2,
                        unsigned short* __restrict__ w1T, unsigned short* __restrict__ w2T,
                        const float* __restrict__ x, unsigned short* __restrict__ AGG,
                        int total_x4) {
    const int bid = blockIdx.x;
    const int t = threadIdx.x;
    if (bid == 0) {
        if (t == 0) {
            int f = 1;
            for (int i = 1; i < 16; i += 2) f &= (e32[i] == 0);
            *flag = f;  // 1 => int64 edges
        }
        for (int i = t; i < 768; i += 256) sums[i] = 0.0f;
    } else if (bid < 8) {
        int i = (bid - 1) * 256 + t;
        if (i < NB) gCur[i] = 0;
    } else if (bid < 136) {
        int i = (bid - 8) * 256 + t;   // < 32768
        int j = i >> 7, k = i & 127;
        w1T[j * 128 + k] = f2bf(W1[k * 256 + j]);
    } else if (bid < 264) {
        int i = (bid - 136) * 256 + t; // < 32768
        int j = i >> 8, k = i & 255;
        w2T[j * 256 + k] = f2bf(W2[k * 128 + j]);
    } else {
        int idx = (bid - 264) * 256 + t;
        if (idx < total_x4) {
            int i = idx >> 5, j4 = (idx & 31) * 4;
            float4 v = *(const float4*)(x + (size_t)i * 128 + j4);
            unsigned lo = (unsigned)f2bf(v.x) | ((unsigned)f2bf(v.y) << 16);
            unsigned hi = (unsigned)f2bf(v.z) | ((unsigned)f2bf(v.w) << 16);
            unsigned short* p = AGG + (size_t)i * 384 + 256 + j4;
            *(unsigned*)(p) = lo;
            *(unsigned*)(p + 2) = hi;
        }
    }
}

// ---------------------------------------------------------------------------
// k_fusew: fold merge-linear into gate weights (fp32 math, one bf16 rounding)
// Gate-permuted physical columns: pj(d,g) = (d>>4)*64 + g*16 + (d&15)
// ---------------------------------------------------------------------------
__global__ void k_fusew(const float* __restrict__ Wm, const float* __restrict__ Wih,
                        const float* __restrict__ Whh, const float* __restrict__ bm,
                        const float* __restrict__ b_ih, const float* __restrict__ b_hh,
                        unsigned short* __restrict__ BtG, float* __restrict__ biasG) {
    const int j = blockIdx.x;
    const int c = threadIdx.x;
    const int g = j >> 7, d = j & 127;
    const int pj = ((d >> 4) << 6) + (g << 4) + (d & 15);
    float acc = 0.0f;
    if (j < 384) {
        const float* wr = Wih + (size_t)j * 128;
        const float* wc = Wm + (size_t)c * 128;
        for (int m = 0; m < 128; m++) acc += wc[m] * wr[m];
    }
    BtG[(size_t)pj * 384 + c] = f2bf(acc);
    if (c < 128) {
        float v = 0.0f;
        if (j < 256) v = Whh[(size_t)j * 128 + c];
        else if (j >= 384) v = Whh[(size_t)(j - 128) * 128 + c];
        BtG[(size_t)pj * 384 + 256 + c] = f2bf(v);
    }
    if (c == 0) {
        float b;
        if (j < 256) b = b_ih[j] + b_hh[j];
        else if (j < 384) b = b_ih[j];
        else b = b_hh[j - 128];
        if (j < 384) {
            const float* wr = Wih + (size_t)j * 128;
            float dd = 0.0f;
            for (int m = 0; m < 128; m++) dd += bm[m] * wr[m];
            b += dd;
        }
        biasG[pj] = b;
    }
}

// ---------------------------------------------------------------------------
// pass A: bin edges into per-bucket windows (bucket = dst>>6, 64 nodes)
// ---------------------------------------------------------------------------
__global__ __launch_bounds__(256) void k_bin(const void* __restrict__ edges_raw,
                                             const int* __restrict__ flag,
                                             int* __restrict__ gCur,
                                             unsigned* __restrict__ binned,
                                             int E, int Nn, int NB) {
    __shared__ int cnt_[MAXNB];
    __shared__ int cur_[MAXNB];
    const int t = threadIdx.x;
    const int e0 = blockIdx.x * 4096;
    for (int i = t; i < NB; i += 256) cnt_[i] = 0;
    __syncthreads();
    const int is64 = *flag;
    for (int k = 0; k < 16; k++) {
        int e = e0 + k * 256 + t;
        if (e < E) {
            int d = is64 ? (int)((const long long*)edges_raw)[(size_t)E + e]
                         : ((const int*)edges_raw)[(size_t)E + e];
            d = min(max(d, 0), Nn - 1);
            atomicAdd(&cnt_[d >> 6], 1);
        }
    }
    __syncthreads();
    for (int i = t; i < NB; i += 256) {
        int c = cnt_[i];
        cur_[i] = (c > 0) ? atomicAdd(&gCur[i], c) : 0;
    }
    __syncthreads();
    for (int k = 0; k < 16; k++) {
        int e = e0 + k * 256 + t;
        if (e < E) {
            int s, d;
            if (is64) {
                s = (int)((const long long*)edges_raw)[e];
                d = (int)((const long long*)edges_raw)[(size_t)E + e];
            } else {
                s = ((const int*)edges_raw)[e];
                d = ((const int*)edges_raw)[(size_t)E + e];
            }
            s = min(max(s, 0), Nn - 1);
            d = min(max(d, 0), Nn - 1);
            int b = d >> 6;
            int p = atomicAdd(&cur_[b], 1);
            if (p < CAPB)
                binned[(size_t)b * CAPB + p] = (unsigned)s | ((unsigned)(d & 63) << 23);
        }
    }
}

// ---------------------------------------------------------------------------
// pass B: per 64-node bucket, LDS CSR, gather-aggregate into AGG cols 0..255
// Node-per-HALF-wave: 8 independent node streams per block (lanes 0-31 own
// node 2w+0, lanes 32-63 own node 2w+1, step 8). Each lane reads 8B
// (4 cols); 8-deep prefetch fills whenever deg>=8 (~98% of nodes at deg~16).
// Tail handled in ONE padded 8-deep round (clamped idx + per-elem select).
// No cross-half shuffles; each half stores its own sum+max rows.
// ---------------------------------------------------------------------------
__global__ __launch_bounds__(256) void k_bagg(const unsigned* __restrict__ binned,
                                              const int* __restrict__ gCur,
                                              const void* __restrict__ edges_raw,
                                              const int* __restrict__ flag,
                                              unsigned short* __restrict__ AGG,
                                              int E, int Nn) {
    __shared__ unsigned lsrc[CAPB];
    __shared__ int deg_[64], off_[64], cur2_[64];
    __shared__ int sa[64], sb[64];
    const int t = threadIdx.x;
    const int wave = t >> 6;
    const int lane = t & 63;
    const int b = blockIdx.x;
    const int node0 = b << 6;
    const int nloc = min(64, Nn - node0);
    const int cnt = gCur[b];
    const int half = lane >> 5;
    const int hl = lane & 31;
    const unsigned c8 = (unsigned)hl * 8u;    // byte offset within 256-B x row
    const int c2 = lane * 2;                  // for slow path

    if (cnt <= CAPB) {
        if (t < 64) deg_[t] = 0;
        __syncthreads();
        for (int i = t; i < cnt; i += 256)
            atomicAdd(&deg_[binned[(size_t)b * CAPB + i] >> 23], 1);
        __syncthreads();
        if (t < 64) sa[t] = deg_[t];
        __syncthreads();
        for (int off = 1; off < 64; off <<= 1) {
            if (t < 64) sb[t] = sa[t] + ((t >= off) ? sa[t - off] : 0);
            __syncthreads();
            if (t < 64) sa[t] = sb[t];
            __syncthreads();
        }
        if (t < 64) {
            off_[t] = sa[t] - deg_[t];
            cur2_[t] = off_[t];
        }
        __syncthreads();
        for (int i = t; i < cnt; i += 256) {
            unsigned e = binned[(size_t)b * CAPB + i];
            int dl = e >> 23;
            int p = atomicAdd(&cur2_[dl], 1);
            lsrc[p] = (e & 0x7FFFFF) * 768u + 512u;   // byte offset of x-row
        }
        __syncthreads();
        const char* AGGb = (const char*)AGG;
        for (int ln = wave * 2 + half; ln < nloc; ln += 8) {
            const int o = off_[ln];
            const int d = deg_[ln];
            float s0 = 0.f, s1 = 0.f, s2 = 0.f, s3 = 0.f;
            float m0 = -INFINITY, m1 = -INFINITY, m2 = -INFINITY, m3 = -INFINITY;
            int e = 0;
            for (; e + 7 < d; e += 8) {
                uint2 v[8];
#pragma unroll
                for (int u = 0; u < 8; u++)
                    v[u] = *(const uint2*)(AGGb + lsrc[o + e + u] + c8);
#pragma unroll
                for (int u = 0; u < 8; u++) {
                    float a = bf2f((unsigned short)(v[u].x & 0xffff));
                    float bb = bf2f((unsigned short)(v[u].x >> 16));
                    float cc = bf2f((unsigned short)(v[u].y & 0xffff));
                    float dd2 = bf2f((unsigned short)(v[u].y >> 16));
                    s0 += a; s1 += bb; s2 += cc; s3 += dd2;
                    m0 = fmaxf(m0, a); m1 = fmaxf(m1, bb);
                    m2 = fmaxf(m2, cc); m3 = fmaxf(m3, dd2);
                }
            }
            if (e < d) {
                // single padded 8-deep round covers the tail (1 latency exposure)
                uint2 v[8];
#pragma unroll
                for (int u = 0; u < 8; u++) {
                    int idx = e + u;
                    if (idx > d - 1) idx = d - 1;
                    v[u] = *(const uint2*)(AGGb + lsrc[o + idx] + c8);
                }
#pragma unroll
                for (int u = 0; u < 8; u++) {
                    bool act = (e + u) < d;
                    float a = bf2f((unsigned short)(v[u].x & 0xffff));
                    float bb = bf2f((unsigned short)(v[u].x >> 16));
                    float cc = bf2f((unsigned short)(v[u].y & 0xffff));
                    float dd2 = bf2f((unsigned short)(v[u].y >> 16));
                    s0 += act ? a : 0.f;  s1 += act ? bb : 0.f;
                    s2 += act ? cc : 0.f; s3 += act ? dd2 : 0.f;
                    m0 = fmaxf(m0, act ? a : -INFINITY);
                    m1 = fmaxf(m1, act ? bb : -INFINITY);
                    m2 = fmaxf(m2, act ? cc : -INFINITY);
                    m3 = fmaxf(m3, act ? dd2 : -INFINITY);
                }
            }
            if (d == 0) { m0 = 0.f; m1 = 0.f; m2 = 0.f; m3 = 0.f; }
            unsigned short* row = AGG + (size_t)(node0 + ln) * 384;
            uint2 sv, mv;
            sv.x = (unsigned)f2bf(s0) | ((unsigned)f2bf(s1) << 16);
            sv.y = (unsigned)f2bf(s2) | ((unsigned)f2bf(s3) << 16);
            mv.x = (unsigned)f2bf(m0) | ((unsigned)f2bf(m1) << 16);
            mv.y = (unsigned)f2bf(m2) | ((unsigned)f2bf(m3) << 16);
            *(uint2*)(row + 4 * hl) = sv;
            *(uint2*)(row + 128 + 4 * hl) = mv;
        }
    } else {
        // overflow slow path (formal correctness; ~never taken)
        const int is64 = *flag;
        for (int ln = wave; ln < nloc; ln += 4) {
            const int node = node0 + ln;
            float sx = 0.f, sy = 0.f;
            float mx = -INFINITY, my = -INFINITY;
            int d = 0;
            for (int e = 0; e < E; e++) {
                int dd = is64 ? (int)((const long long*)edges_raw)[(size_t)E + e]
                              : ((const int*)edges_raw)[(size_t)E + e];
                dd = min(max(dd, 0), Nn - 1);
                if (dd == node) {
                    int s = is64 ? (int)((const long long*)edges_raw)[e]
                                 : ((const int*)edges_raw)[e];
                    s = min(max(s, 0), Nn - 1);
                    unsigned v0 = *(const unsigned*)(AGG + (size_t)s * 384 + 256 + c2);
                    float ax = bf2f((unsigned short)(v0 & 0xffff));
                    float ay = bf2f((unsigned short)(v0 >> 16));
                    sx += ax; sy += ay;
                    mx = fmaxf(mx, ax); my = fmaxf(my, ay);
                    d++;
                }
            }
            if (d == 0) { mx = 0.f; my = 0.f; }
            unsigned short* row = AGG + (size_t)node * 384;
            *(unsigned*)(row + c2) = (unsigned)f2bf(sx) | ((unsigned)f2bf(sy) << 16);
            *(unsigned*)(row + 128 + c2) = (unsigned)f2bf(mx) | ((unsigned)f2bf(my) << 16);
        }
    }
}

// ---------------------------------------------------------------------------
// bf16 MFMA GEMM, 128x128 tile, 4 waves, 4x4 of 16x16x32 MFMA. (proven r4)
// Non-AFFINE path: counted-vmcnt 2-deep pipeline via global_load_lds.
// AFFINE path: reg-staged A (BN1 transform) + __syncthreads.
// GRUE epilogue: gate-permuted columns, in-register GRU -> h bf16.
// ---------------------------------------------------------------------------
template <int AFFINE, int LEAKY, int STATS, int GRUE>
__global__ __launch_bounds__(256) void k_mgemm(
    const unsigned short* __restrict__ A, int lda,
    const unsigned short* __restrict__ Bt,
    const float* __restrict__ bias,
    const float* __restrict__ sumA, const float* __restrict__ sqA,
    const float* __restrict__ gA, const float* __restrict__ beA,
    unsigned short* __restrict__ Cb, int ldc,
    int M, int K, float* __restrict__ sumO, float* __restrict__ sqO, float invN,
    const unsigned short* __restrict__ Xb) {
    __shared__ unsigned short ABs[2][2][4096];  // [buf][A|B][128*32]
    __shared__ float sc1[256], sh1[256];
    __shared__ float ssum[128], ssq[128];
    unsigned short* RP = &ABs[0][0][0];         // epilogue repack region

    const int t = threadIdx.x;
    const int lane = t & 63;
    const int wave = t >> 6;
    const int wr = (wave >> 1) * 64;
    const int wc = (wave & 1) * 64;
    const int quad = lane >> 4;
    const int l16 = lane & 15;
    const int sig = (l16 >> 1) & 3;             // fragment-read swizzle

    // XCD-grouped bijective remap (m204)
    const int ncb = gridDim.x;
    const int nwg = ncb * gridDim.y;
    int lin = blockIdx.y * ncb + blockIdx.x;
    const int qq = nwg >> 3, rr = nwg & 7;
    const int xcd = lin & 7, pos = lin >> 3;
    const int nl = (xcd < rr ? xcd * (qq + 1) : rr * (qq + 1) + (xcd - rr) * qq) + pos;
    const int j0 = (nl % ncb) * 128;
    const int r0 = (nl / ncb) * 128;

    if (AFFINE) {
        float m = sumA[t] * invN;
        float v = sqA[t] * invN - m * m;
        if (v < 0.f) v = 0.f;
        float rs = rsqrtf(v + 1e-5f);
        float sc = gA[t] * rs;
        sc1[t] = sc;
        sh1[t] = beA[t] - m * sc;
    }
    if (STATS && t < 128) { ssum[t] = 0.f; ssq[t] = 0.f; }
    if (AFFINE || STATS) __syncthreads();

    f32x4 acc[4][4];
#pragma unroll
    for (int i = 0; i < 4; i++)
#pragma unroll
        for (int j = 0; j < 4; j++) acc[i][j] = (f32x4){0.f, 0.f, 0.f, 0.f};

    const int rowl = lane >> 2;
    const int gsw8 = (((lane & 3) ^ ((lane >> 3) & 3))) * 8;

    const int srow = t >> 2;
    const int sg8 = (t & 3) * 8;
    const int swz8 = (((t & 3) ^ ((t >> 3) & 3))) * 8;
    float4 areg[2];

    auto stageA = [&](int buf, int k0) {
#pragma unroll
        for (int p = 0; p < 2; p++) {
            int row = (wave * 2 + p) * 16 + rowl;
            int gr = r0 + row;
            if (gr >= M) gr = M - 1;
            gld16(A + (size_t)gr * lda + k0 + gsw8,
                  &ABs[buf][0][(wave * 2 + p) * 512]);
        }
    };
    auto stageB = [&](int buf, int k0) {
#pragma unroll
        for (int p = 0; p < 2; p++) {
            int row = (wave * 2 + p) * 16 + rowl;
            gld16(Bt + (size_t)(j0 + row) * K + k0 + gsw8,
                  &ABs[buf][1][(wave * 2 + p) * 512]);
        }
    };
    auto loadA = [&](int k0) {
#pragma unroll
        for (int p = 0; p < 2; p++) {
            int gr = r0 + p * 64 + srow;
            areg[p] = make_float4(0.f, 0.f, 0.f, 0.f);
            if (gr < M) areg[p] = *(const float4*)(A + (size_t)gr * lda + k0 + sg8);
        }
    };
    auto writeA = [&](int buf, int k0) {
        union U8 { float4 f; unsigned short u[8]; } uv;
#pragma unroll
        for (int p = 0; p < 2; p++) {
            uv.f = areg[p];
#pragma unroll
            for (int q = 0; q < 8; q++) {
                float f = bf2f(uv.u[q]) * sc1[k0 + sg8 + q] + sh1[k0 + sg8 + q];
                uv.u[q] = f2bf(f);
            }
            *(float4*)&ABs[buf][0][(p * 64 + srow) * 32 + swz8] = uv.f;
        }
    };

    if (!AFFINE) {
        // ---- counted-vmcnt pipeline: 2 tiles staged ahead, never drain to 0 ----
        stageA(0, 0); stageB(0, 0);
        if (32 < K) { stageA(1, 32); stageB(1, 32); }
        for (int k0 = 0; k0 < K; k0 += 32) {
            const int cur = (k0 >> 5) & 1;
            if (k0 + 32 < K)
                asm volatile("s_waitcnt vmcnt(4)\n\ts_barrier" ::: "memory");
            else
                asm volatile("s_waitcnt vmcnt(0)\n\ts_barrier" ::: "memory");
            bf16x8 af[4], bfr[4];
#pragma unroll
            for (int i = 0; i < 4; i++) {
                af[i]  = *(bf16x8*)&ABs[cur][0][(wr + i * 16 + l16) * 32 + (quad ^ sig) * 8];
                bfr[i] = *(bf16x8*)&ABs[cur][1][(wc + i * 16 + l16) * 32 + (quad ^ sig) * 8];
            }
            asm volatile("s_waitcnt lgkmcnt(0)\n\ts_barrier" ::: "memory");
            if (k0 + 64 < K) { stageA(cur, k0 + 64); stageB(cur, k0 + 64); }
#pragma unroll
            for (int mt = 0; mt < 4; mt++)
#pragma unroll
                for (int nt = 0; nt < 4; nt++)
                    acc[mt][nt] = __builtin_amdgcn_mfma_f32_16x16x32_bf16(
                        af[mt], bfr[nt], acc[mt][nt], 0, 0, 0);
        }
    } else {
        // ---- AFFINE: reg-staged A + __syncthreads double-buffer (proven) ----
        loadA(0); writeA(0, 0);
        stageB(0, 0);
        __syncthreads();
        int buf = 0;
        for (int k0 = 0; k0 < K; k0 += 32) {
            const int kn = k0 + 32;
            const bool hasNext = kn < K;
            if (hasNext) {
                loadA(kn);
                stageB(buf ^ 1, kn);
            }
            bf16x8 af[4], bfr[4];
#pragma unroll
            for (int i = 0; i < 4; i++) {
                af[i]  = *(bf16x8*)&ABs[buf][0][(wr + i * 16 + l16) * 32 + (quad ^ sig) * 8];
                bfr[i] = *(bf16x8*)&ABs[buf][1][(wc + i * 16 + l16) * 32 + (quad ^ sig) * 8];
            }
#pragma unroll
            for (int mt = 0; mt < 4; mt++)
#pragma unroll
                for (int nt = 0; nt < 4; nt++)
                    acc[mt][nt] = __builtin_amdgcn_mfma_f32_16x16x32_bf16(
                        af[mt], bfr[nt], acc[mt][nt], 0, 0, 0);
            if (hasNext) writeA(buf ^ 1, kn);
            __syncthreads();
            buf ^= 1;
        }
    }

    if (GRUE) {
        // ---- GRU epilogue: nt=gate (0:r 1:z 2:i_n 3:h_n), dim = dimb+l16 ----
        const int dimb = (j0 + wc) >> 2;       // global hidden-dim base for wave
        const int dloc = (wc >> 2) + l16;      // 0..31 block-local dim
        const float bR = bias[j0 + wc + l16];
        const float bZ = bias[j0 + wc + 16 + l16];
        const float bI = bias[j0 + wc + 32 + l16];
        const float bH = bias[j0 + wc + 48 + l16];
#pragma unroll
        for (int mt = 0; mt < 4; mt++) {
#pragma unroll
            for (int reg = 0; reg < 4; reg++) {
                int rloc = wr + mt * 16 + quad * 4 + reg;
                int grow = r0 + rloc;
                int gi = grow < M ? grow : M - 1;
                float r = fsigm(acc[mt][0][reg] + bR);
                float z = fsigm(acc[mt][1][reg] + bZ);
                float nn = ftanh(acc[mt][2][reg] + bI + r * (acc[mt][3][reg] + bH));
                float xv = bf2f(Xb[(size_t)gi * 384 + 256 + dimb + l16]);
                float h = (1.0f - z) * nn + z * xv;
                RP[rloc * 40 + dloc] = f2bf(h);
            }
        }
        __syncthreads();
#pragma unroll
        for (int p = 0; p < 2; p++) {
            int id = p * 256 + t;              // 0..511 = 128 rows x 4 chunks
            int rloc = id >> 2, ck = id & 3;
            int grow = r0 + rloc;
            if (grow < M)
                *(float4*)(Cb + (size_t)grow * ldc + (j0 >> 2) + ck * 8) =
                    *(const float4*)&RP[rloc * 40 + ck * 8];
        }
        return;
    }

    // ---- standard epilogue: repack via LDS, coalesced 16B stores ----
#pragma unroll
    for (int half = 0; half < 2; half++) {
        if (wr == half * 64) {
#pragma unroll
            for (int nt = 0; nt < 4; nt++) {
                int colLoc = wc + nt * 16 + l16;
                float bv = bias[j0 + colLoc];
                float s = 0.f, q = 0.f;
#pragma unroll
                for (int mt = 0; mt < 4; mt++) {
#pragma unroll
                    for (int reg = 0; reg < 4; reg++) {
                        int rloc = mt * 16 + quad * 4 + reg;
                        float v = acc[mt][nt][reg] + bv;
                        if (LEAKY) v = (v >= 0.f) ? v : 0.01f * v;
                        if (STATS && (r0 + half * 64 + rloc) < M) { s += v; q += v * v; }
                        RP[rloc * 128 + colLoc] = f2bf(v);
                    }
                }
                if (STATS) {
                    atomicAdd(&ssum[colLoc], s);
                    atomicAdd(&ssq[colLoc], q);
                }
            }
        }
        __syncthreads();
#pragma unroll
        for (int p = 0; p < 4; p++) {
            int id = p * 256 + t;      // 0..1023 = 64 rows x 16 chunks
            int rloc = id >> 4;
            int ck = id & 15;
            int grow = r0 + half * 64 + rloc;
            if (grow < M)
                *(float4*)(Cb + (size_t)grow * ldc + j0 + ck * 8) =
                    *(const float4*)&RP[rloc * 128 + ck * 8];
        }
        __syncthreads();
    }
    if (STATS && t < 128) {
        atomicAdd(&sumO[j0 + t], ssum[t]);
        atomicAdd(&sqO[j0 + t], ssq[t]);
    }
}

// out(fp32) = bf2f(ypre)*scale2 + shift2 (BN2 finalize inline), 4 elems/thread
__global__ void k_affine2(const unsigned short* __restrict__ ypre, float* __restrict__ out,
                          const float* __restrict__ sum2, const float* __restrict__ sq2,
                          const float* __restrict__ g2, const float* __restrict__ be2,
                          int total4, float invN) {
    __shared__ float sc[128], sh[128];
    int t = threadIdx.x;
    if (t < 128) {
        float m = sum2[t] * invN;
        float v = sq2[t] * invN - m * m;
        if (v < 0.f) v = 0.f;
        float rs = rsqrtf(v + 1e-5f);
        float s = g2[t] * rs;
        sc[t] = s;
        sh[t] = be2[t] - m * s;
    }
    __syncthreads();
    int idx = blockIdx.x * 256 + t;
    if (idx >= total4) return;
    int i4 = idx * 4;
    int c = i4 & 127;
    unsigned u0 = *(const unsigned*)(ypre + i4);
    unsigned u1 = *(const unsigned*)(ypre + i4 + 2);
    float4 o;
    o.x = bf2f((unsigned short)(u0 & 0xffff)) * sc[c]     + sh[c];
    o.y = bf2f((unsigned short)(u0 >> 16))    * sc[c + 1] + sh[c + 1];
    o.z = bf2f((unsigned short)(u1 & 0xffff)) * sc[c + 2] + sh[c + 2];
    o.w = bf2f((unsigned short)(u1 >> 16))    * sc[c + 3] + sh[c + 3];
    *(float4*)(out + i4) = o;
}

// ---------------------------------------------------------------------------
extern "C" void kernel_launch(void* const* d_in, const int* in_sizes, int n_in,
                              void* d_out, int out_size, void* d_ws, size_t ws_size,
                              hipStream_t stream) {
    const float* x       = (const float*)d_in[0];
    const void*  edges   = d_in[1];
    const float* W_merge = (const float*)d_in[2];
    const float* b_merge = (const float*)d_in[3];
    const float* W_ih    = (const float*)d_in[4];
    const float* W_hh    = (const float*)d_in[5];
    const float* b_ih    = (const float*)d_in[6];
    const float* b_hh    = (const float*)d_in[7];
    const float* W1      = (const float*)d_in[8];
    const float* b1      = (const float*)d_in[9];
    const float* g1      = (const float*)d_in[10];
    const float* be1     = (const float*)d_in[11];
    const float* W2      = (const float*)d_in[12];
    const float* b2      = (const float*)d_in[13];
    const float* g2      = (const float*)d_in[14];
    const float* be2     = (const float*)d_in[15];

    const int N = in_sizes[0] / DD;
    const int E = in_sizes[1] / 2;
    float* out = (float*)d_out;

    size_t need = ((size_t)640 * N + 120000) * sizeof(float);
    if (ws_size < need) {
        k_wsfail<<<(out_size + 255) / 256, 256, 0, stream>>>(
            out, (float)(ws_size >> 20), out_size);
        return;
    }

    const int NB = (N + 63) >> 6;   // 64-node buckets

    float* ws = (float*)d_ws;
    // [0,192N): AGG bf16 Nx384 (sum|max|x) -> later y1b bf16 Nx256 at [0,128N),
    //                                         ypre bf16 Nx128 at [128N,192N)
    // [448N,512N): h bf16 Nx128
    // [512N,...): binned (NB*CAPB uints) + gCur + weights + sums
    unsigned short* AGG  = (unsigned short*)ws;
    unsigned short* y1b  = (unsigned short*)ws;
    unsigned short* ypre = (unsigned short*)(ws + (size_t)128 * N);
    unsigned short* hb16 = (unsigned short*)(ws + (size_t)448 * N);

    unsigned* binned = (unsigned*)(ws + (size_t)512 * N);
    int* gCur = (int*)(binned + (size_t)NB * CAPB);

    float* wbase = (float*)(gCur + NB + 64);
    unsigned short* BtG = (unsigned short*)wbase;                 // 512*384 el
    unsigned short* w1T = (unsigned short*)(wbase + 98304);       // 32768 el
    unsigned short* w2T = (unsigned short*)(wbase + 98304 + 16384);
    float* biasG = wbase + 98304 + 32768;   // 512
    float* sums  = biasG + 512;             // 768
    float* sum1 = sums, *sq1 = sums + 256, *sum2 = sums + 512, *sq2 = sums + 640;
    int*   flag  = (int*)(sums + 768);

    const int nrb  = (N + 127) / 128;
    const int ncvt4 = (N * 32 + 255) / 256;
    const float invN = 1.0f / (float)N;

    // 1. setup (detect, zeros, w1T/w2T, x->AGG)
    k_setup<<<264 + ncvt4, 256, 0, stream>>>(
        (const int*)edges, flag, sums, gCur, NB, W1, W2, w1T, w2T, x, AGG, N * 32);
    // 2. fused gate weights, gate-permuted columns (fp32 dot, one bf16 rounding)
    k_fusew<<<512, 256, 0, stream>>>(W_merge, W_ih, W_hh, b_merge, b_ih, b_hh, BtG, biasG);
    // 3. bin edges
    k_bin<<<(E + 4095) / 4096, 256, 0, stream>>>(edges, flag, gCur, binned, E, N, NB);
    // 4. per-bucket aggregate -> AGG cols 0..255
    k_bagg<<<NB, 256, 0, stream>>>(binned, gCur, edges, flag, AGG, E, N);
    // 5. fused G2'+GRU: h = GRU(AGG @ BtG + biasG, x)  (K=384, F=512 -> 128)
    k_mgemm<0, 0, 0, 1><<<dim3(4, nrb), 256, 0, stream>>>(
        AGG, 384, BtG, biasG, nullptr, nullptr, nullptr, nullptr,
        hb16, 128, N, 384, nullptr, nullptr, invN, AGG);
    // 6. G4: y1b = leaky(h @ w1T + b1) + stats1  (K=128, F=256)
    k_mgemm<0, 1, 1, 0><<<dim3(2, nrb), 256, 0, stream>>>(
        hb16, 128, w1T, b1, nullptr, nullptr, nullptr, nullptr,
        y1b, 256, N, 128, sum1, sq1, invN, nullptr);
    // 7. G5: ypre = leaky(bn1(y1b) @ w2T + b2) + stats2  (K=256, F=128)
    k_mgemm<1, 1, 1, 0><<<dim3(1, nrb), 256, 0, stream>>>(
        y1b, 256, w2T, b2, sum1, sq1, g1, be1,
        ypre, 128, N, 256, sum2, sq2, invN, nullptr);
    // 8. BN2 finalize + affine -> fp32 out (4 elems/thread)
    k_affine2<<<ncvt4, 256, 0, stream>>>(ypre, out, sum2, sq2, g2, be2, N * 32, invN);
}